// Round 3
// baseline (345.833 us; speedup 1.0000x reference)
//
#include <hip/hip_runtime.h>
#include <math.h>

#define T_TOKENS 16384
#define D_DIM    2048
#define E_EXP    64
#define TOPK     8

// ---------------- Kernel 1: partial logits GEMM ----------------
// grid (T/64, ns). Block: 256 threads = 4 waves. Lane = token (64 tokens/block);
// wave w owns experts [w*16, w*16+16). Per 64-k chunk:
//   - x tile [64 tok][64 k] staged coalesced into LDS (row stride 65 -> the
//     per-lane transpose read xl[lane*65+k] is bank-conflict-free: bank=(lane+k)%32)
//   - xr[64] pulled to registers (ds_read2-mergeable)
//   - gw read at WAVE-UNIFORM addresses -> s_load (scalar pipe, sK$/L2-resident);
//     FMA is v_fmac(vacc, s_g, v_xr) -> no LDS, no VGPR loads for g.

#define TT   64
#define KC   64
#define XS   65                 // conflict-free transpose stride

__global__ __launch_bounds__(256, 4) void moe_logits_kernel(
    const float* __restrict__ x, const float* __restrict__ gw,
    float* __restrict__ part, float* __restrict__ counts_zero, int ns)
{
  __shared__ float xl[TT * XS];   // 16640 B

  const int tid  = threadIdx.x;
  const int lane = tid & 63;
  const int e_base = __builtin_amdgcn_readfirstlane(tid >> 6) * 16;  // uniform
  const int ks   = blockIdx.y;
  const int tok0 = blockIdx.x * TT;
  const int ksz  = D_DIM / ns;
  const int k0   = ks * ksz;
  const int nchunk = ksz / KC;

  if (blockIdx.x == 0 && ks == 0 && tid < E_EXP) counts_zero[tid] = 0.0f;

  const int srow = tid >> 4;      // staging row 0..15 (+16p)
  const int sc4  = tid & 15;      // staging float4 col

  float acc[16];
  #pragma unroll
  for (int e = 0; e < 16; ++e) acc[e] = 0.0f;

  #pragma unroll 1
  for (int c = 0; c < nchunk; ++c) {
    const int kc0 = k0 + c * KC;

    // ---- stage x tile: coalesced global b128, scalar LDS writes (<=2-way) ----
    #pragma unroll
    for (int p = 0; p < 4; ++p) {
      const int row = srow + 16 * p;
      float4 v = *(const float4*)&x[(size_t)(tok0 + row) * D_DIM + kc0 + sc4 * 4];
      float* d = &xl[row * XS + sc4 * 4];
      d[0] = v.x; d[1] = v.y; d[2] = v.z; d[3] = v.w;
    }
    __syncthreads();

    // ---- my token's 64 k values -> registers (conflict-free) ----
    float xr[KC];
    #pragma unroll
    for (int k = 0; k < KC; ++k) xr[k] = xl[lane * XS + k];

    // ---- 16 experts x 64 k: g via scalar loads (uniform addr), FMA s*v ----
    const float* gp0 = gw + (size_t)e_base * D_DIM + kc0;
    #pragma unroll
    for (int e = 0; e < 16; ++e) {
      const float* gp = gp0 + (size_t)e * D_DIM;
      float s = acc[e];
      #pragma unroll
      for (int k = 0; k < KC; ++k) s = fmaf(gp[k], xr[k], s);
      acc[e] = s;
    }
    __syncthreads();
  }

  // ---- store partials: part[ks][tok][e_base..e_base+15] ----
  float* pp = &part[((size_t)ks * T_TOKENS + tok0 + lane) * E_EXP + e_base];
  #pragma unroll
  for (int j = 0; j < 4; ++j)
    *(float4*)&pp[4 * j] = make_float4(acc[4*j], acc[4*j+1], acc[4*j+2], acc[4*j+3]);
}

// ---------------- Kernel 2: reduce partials + bias, top-8, softmax, counts ----
__global__ __launch_bounds__(256) void topk_kernel(
    const float* __restrict__ part, const float* __restrict__ bias,
    float* __restrict__ out, int ns)
{
  __shared__ unsigned hist[E_EXP];
  const int tid = threadIdx.x;
  const int t = blockIdx.x * 256 + tid;
  if (tid < E_EXP) hist[tid] = 0;
  __syncthreads();

  float l[E_EXP];
  #pragma unroll
  for (int j = 0; j < E_EXP / 4; ++j) {
    float4 b = *(const float4*)&bias[j * 4];
    l[4*j] = b.x; l[4*j+1] = b.y; l[4*j+2] = b.z; l[4*j+3] = b.w;
  }
  for (int ks = 0; ks < ns; ++ks) {
    const float4* p = (const float4*)&part[((size_t)ks * T_TOKENS + t) * E_EXP];
    #pragma unroll
    for (int j = 0; j < E_EXP / 4; ++j) {
      float4 v = p[j];
      l[4*j] += v.x; l[4*j+1] += v.y; l[4*j+2] += v.z; l[4*j+3] += v.w;
    }
  }

  float tv[TOPK]; int tix[TOPK];
  unsigned long long used = 0ull;
  #pragma unroll
  for (int k = 0; k < TOPK; ++k) {
    float best = -INFINITY; int bi = 0;
    #pragma unroll
    for (int j = 0; j < E_EXP; ++j) {
      bool ok = (((used >> j) & 1ull) == 0ull) && (l[j] > best);  // strict >: lowest index wins ties
      best = ok ? l[j] : best;
      bi   = ok ? j : bi;
    }
    tv[k] = best; tix[k] = bi;
    used |= (1ull << bi);
  }

  float m = tv[0], s = 0.0f, w[TOPK];
  #pragma unroll
  for (int k = 0; k < TOPK; ++k) { w[k] = expf(tv[k] - m); s += w[k]; }
  float inv = 1.0f / s;

  #pragma unroll
  for (int k = 0; k < TOPK; ++k) {
    out[(size_t)t * TOPK + k] = (float)tix[k];                        // indices as fp32
    out[(size_t)T_TOKENS * TOPK + (size_t)t * TOPK + k] = w[k] * inv; // weights
  }

  #pragma unroll
  for (int k = 0; k < TOPK; ++k) atomicAdd(&hist[tix[k]], 1u);
  __syncthreads();
  if (tid < E_EXP)
    atomicAdd(&out[2 * (size_t)T_TOKENS * TOPK + tid], (float)hist[tid]);
}

extern "C" void kernel_launch(void* const* d_in, const int* in_sizes, int n_in,
                              void* d_out, int out_size, void* d_ws, size_t ws_size,
                              hipStream_t stream) {
  const float* x    = (const float*)d_in[0];
  const float* gw   = (const float*)d_in[1];
  const float* bias = (const float*)d_in[2];
  float* out  = (float*)d_out;
  float* part = (float*)d_ws;

  const size_t slice_bytes = (size_t)T_TOKENS * E_EXP * sizeof(float);  // 4 MB
  int ns = 1;
  if (ws_size >= 4 * slice_bytes)      ns = 4;   // 16 MB scratch
  else if (ws_size >= 2 * slice_bytes) ns = 2;

  moe_logits_kernel<<<dim3(T_TOKENS / TT, ns), dim3(256), 0, stream>>>(
      x, gw, part, out + 2 * (size_t)T_TOKENS * TOPK, ns);
  topk_kernel<<<dim3(T_TOKENS / 256), dim3(256), 0, stream>>>(part, bias, out, ns);
}

// Round 4
// 236.341 us; speedup vs baseline: 1.4633x; 1.4633x over previous
//
#include <hip/hip_runtime.h>
#include <math.h>

#define T_TOKENS 16384
#define D_DIM    2048
#define E_EXP    64
#define TOPK     8

// ---------------- Kernel 1: partial logits GEMM ----------------
// grid (T/64, ns), 256 threads. Block tile 64 tok x 64 exp, thread tile 4x4.
// LDS holds BOTH operands transposed: xl[k][t], gl[k][e], stride 68.
//  - staging writes: lane (srow=tid>>2, sq=tid&3) -> bank (16sq+4j+srow)%32
//    = all 32 banks x 2-way = conflict-free (m136: 2-way is free).
//  - compute reads at fixed k: x frag 16 distinct b128 (4-fold broadcast),
//    g frag 4 distinct b128 (16-fold broadcast) -> ~320B distinct/wave/k
//    ≈4 cyc vs 8 FMA CU-cyc -> VALU-bound.

#define TT   64
#define KC   32
#define XT   68
#define GT   68

__global__ __launch_bounds__(256, 4) void moe_logits_kernel(
    const float* __restrict__ x, const float* __restrict__ gw,
    float* __restrict__ part, float* __restrict__ counts_zero, int ns)
{
  __shared__ float xl[KC * XT];   // 8704 B
  __shared__ float gl[KC * GT];   // 8704 B

  const int tid  = threadIdx.x;
  const int tg   = tid & 15;      // token group: tokens tg*4..tg*4+3
  const int eg   = tid >> 4;      // expert group: experts eg*4..eg*4+3
  const int ks   = blockIdx.y;
  const int tok0 = blockIdx.x * TT;
  const int ksz  = D_DIM / ns;
  const int k0   = ks * ksz;
  const int nchunk = ksz / KC;

  if (blockIdx.x == 0 && ks == 0 && tid < E_EXP) counts_zero[tid] = 0.0f;

  const int srow = tid >> 2;      // 0..63: token (x) or expert (g) row
  const int sq   = tid & 3;       // float4 quarter along k

  float4 acc[4];
  #pragma unroll
  for (int j = 0; j < 4; ++j) acc[j] = make_float4(0.f, 0.f, 0.f, 0.f);

  #pragma unroll 1
  for (int c = 0; c < nchunk; ++c) {
    const int kc0 = k0 + c * KC;

    // ---- stage x[64 tok][32 k] -> xl[k][t] ----
    #pragma unroll
    for (int p = 0; p < 2; ++p) {
      const int kk = (sq + 4 * p) * 4;
      float4 v = *(const float4*)&x[(size_t)(tok0 + srow) * D_DIM + kc0 + kk];
      xl[(kk + 0) * XT + srow] = v.x;
      xl[(kk + 1) * XT + srow] = v.y;
      xl[(kk + 2) * XT + srow] = v.z;
      xl[(kk + 3) * XT + srow] = v.w;
    }
    // ---- stage gw[64 e][32 k] -> gl[k][e] ----
    #pragma unroll
    for (int p = 0; p < 2; ++p) {
      const int kk = (sq + 4 * p) * 4;
      float4 v = *(const float4*)&gw[(size_t)srow * D_DIM + kc0 + kk];
      gl[(kk + 0) * GT + srow] = v.x;
      gl[(kk + 1) * GT + srow] = v.y;
      gl[(kk + 2) * GT + srow] = v.z;
      gl[(kk + 3) * GT + srow] = v.w;
    }
    __syncthreads();

    // ---- compute: 32 k-steps of 4x4 outer product ----
    #pragma unroll
    for (int k = 0; k < KC; ++k) {
      float4 xv = *(const float4*)&xl[k * XT + tg * 4];
      float4 gv = *(const float4*)&gl[k * GT + eg * 4];
      acc[0].x = fmaf(xv.x, gv.x, acc[0].x); acc[0].y = fmaf(xv.x, gv.y, acc[0].y);
      acc[0].z = fmaf(xv.x, gv.z, acc[0].z); acc[0].w = fmaf(xv.x, gv.w, acc[0].w);
      acc[1].x = fmaf(xv.y, gv.x, acc[1].x); acc[1].y = fmaf(xv.y, gv.y, acc[1].y);
      acc[1].z = fmaf(xv.y, gv.z, acc[1].z); acc[1].w = fmaf(xv.y, gv.w, acc[1].w);
      acc[2].x = fmaf(xv.z, gv.x, acc[2].x); acc[2].y = fmaf(xv.z, gv.y, acc[2].y);
      acc[2].z = fmaf(xv.z, gv.z, acc[2].z); acc[2].w = fmaf(xv.z, gv.w, acc[2].w);
      acc[3].x = fmaf(xv.w, gv.x, acc[3].x); acc[3].y = fmaf(xv.w, gv.y, acc[3].y);
      acc[3].z = fmaf(xv.w, gv.z, acc[3].z); acc[3].w = fmaf(xv.w, gv.w, acc[3].w);
    }
    __syncthreads();
  }

  // ---- store partials part[ks][tok][e] ----
  #pragma unroll
  for (int j = 0; j < 4; ++j) {
    const size_t t = (size_t)tok0 + tg * 4 + j;
    *(float4*)&part[((size_t)ks * T_TOKENS + t) * E_EXP + eg * 4] = acc[j];
  }
}

// ---------------- Kernel 2: reduce + bias, top-8, softmax, counts ----------------
// 256 blocks x 64 threads (thread-per-token) -> all 256 CUs participate.
__global__ __launch_bounds__(64) void topk_kernel(
    const float* __restrict__ part, const float* __restrict__ bias,
    float* __restrict__ out, int ns)
{
  __shared__ unsigned hist[E_EXP];
  const int tid = threadIdx.x;            // 0..63
  const int t = blockIdx.x * 64 + tid;
  hist[tid] = 0;
  __syncthreads();

  float l[E_EXP];
  #pragma unroll
  for (int j = 0; j < E_EXP / 4; ++j) {
    float4 b = *(const float4*)&bias[j * 4];
    l[4*j] = b.x; l[4*j+1] = b.y; l[4*j+2] = b.z; l[4*j+3] = b.w;
  }
  for (int ks = 0; ks < ns; ++ks) {
    const float4* p = (const float4*)&part[((size_t)ks * T_TOKENS + t) * E_EXP];
    #pragma unroll
    for (int j = 0; j < E_EXP / 4; ++j) {
      float4 v = p[j];
      l[4*j] += v.x; l[4*j+1] += v.y; l[4*j+2] += v.z; l[4*j+3] += v.w;
    }
  }

  float tv[TOPK]; int tix[TOPK];
  unsigned long long used = 0ull;
  #pragma unroll
  for (int k = 0; k < TOPK; ++k) {
    float best = -INFINITY; int bi = 0;
    #pragma unroll
    for (int j = 0; j < E_EXP; ++j) {
      bool ok = (((used >> j) & 1ull) == 0ull) && (l[j] > best);  // strict >: lowest index wins ties
      best = ok ? l[j] : best;
      bi   = ok ? j : bi;
    }
    tv[k] = best; tix[k] = bi;
    used |= (1ull << bi);
  }

  float m = tv[0], s = 0.0f, w[TOPK];
  #pragma unroll
  for (int k = 0; k < TOPK; ++k) { w[k] = expf(tv[k] - m); s += w[k]; }
  float inv = 1.0f / s;

  #pragma unroll
  for (int k = 0; k < TOPK; ++k) {
    out[(size_t)t * TOPK + k] = (float)tix[k];                        // indices as fp32
    out[(size_t)T_TOKENS * TOPK + (size_t)t * TOPK + k] = w[k] * inv; // weights
  }

  #pragma unroll
  for (int k = 0; k < TOPK; ++k) atomicAdd(&hist[tix[k]], 1u);
  __syncthreads();
  atomicAdd(&out[2 * (size_t)T_TOKENS * TOPK + tid], (float)hist[tid]);
}

extern "C" void kernel_launch(void* const* d_in, const int* in_sizes, int n_in,
                              void* d_out, int out_size, void* d_ws, size_t ws_size,
                              hipStream_t stream) {
  const float* x    = (const float*)d_in[0];
  const float* gw   = (const float*)d_in[1];
  const float* bias = (const float*)d_in[2];
  float* out  = (float*)d_out;
  float* part = (float*)d_ws;

  const size_t slice_bytes = (size_t)T_TOKENS * E_EXP * sizeof(float);  // 4 MB
  int ns = 1;
  if (ws_size >= 4 * slice_bytes)      ns = 4;   // 16 MB scratch
  else if (ws_size >= 2 * slice_bytes) ns = 2;

  moe_logits_kernel<<<dim3(T_TOKENS / TT, ns), dim3(256), 0, stream>>>(
      x, gw, part, out + 2 * (size_t)T_TOKENS * TOPK, ns);
  topk_kernel<<<dim3(T_TOKENS / 64), dim3(64), 0, stream>>>(part, bias, out, ns);
}